// Round 2
// baseline (191.635 us; speedup 1.0000x reference)
//
#include <hip/hip_runtime.h>

// ---------------------------------------------------------------------------
// FNNAttention (Bahdanau additive attention), fp32.
// B=4, Q=256, M=256, QS=KS=H=512.
// Pipeline:
//   1. mask_norm  : normalize mask (bool-bytes or int32) -> int32 in ws
//   2. proj_gemm  : q = query@Wq^T+bq ; k = memory@Wk^T+bk   (z-fused)
//   3. attn_fused : logits (skip masked m), softmax, weights-out, attns
//   4. out_gemm   : out = tanh([query|attns]@Wo^T + bo)
// ---------------------------------------------------------------------------

#define B_   4
#define Q_   256
#define M_   256
#define H_   512
#define QS_  512
#define KS_  512

__device__ __forceinline__ float fast_exp2(float x) { return __builtin_amdgcn_exp2f(x); }

__device__ __forceinline__ float tanh_fast(float x) {
    // tanh(x) = 1 - 2/(exp(2x)+1); exp(2x) = exp2(x * 2*log2(e))
    float e = fast_exp2(x * 2.8853900817779268f);
    return 1.0f - 2.0f * __builtin_amdgcn_rcpf(e + 1.0f);
}

// ---------------------------------------------------------------------------
// Mask normalization: detect layout (1-byte bool vs int32) and write int32.
// Reads only the first n BYTES (safe for both layouts). If any byte at
// position i (i%4 != 0) is nonzero, layout is bool-bytes.
// ---------------------------------------------------------------------------
__global__ __launch_bounds__(256) void mask_norm(const unsigned char* __restrict__ raw,
                                                 int* __restrict__ out, int n) {
    __shared__ int flags[4];
    const int tid = threadIdx.x;
    int any = 0;
    for (int i = tid; i < n; i += 256)
        if ((i & 3) && raw[i]) any = 1;
    int wany = __any(any);
    if ((tid & 63) == 0) flags[tid >> 6] = wany ? 1 : 0;
    __syncthreads();
    const int isbool = flags[0] | flags[1] | flags[2] | flags[3];
    const int* ri = (const int*)raw;
    for (int i = tid; i < n; i += 256)
        out[i] = isbool ? (int)raw[i] : ri[i];
}

// ---------------------------------------------------------------------------
// Tiled NT GEMM: C[r][c] = act( sum_k A(r,k) * W[c][k] + bias[c] )
// A(r,k) = k < KA0 ? A0[r*KA0+k] : A1[r*KA0 + (k-KA0)]   (virtual concat)
// BM=BN=64, BK=32, 256 threads, 4x4 micro-tile.
// ---------------------------------------------------------------------------
#define GBM 64
#define GBN 64
#define GBK 32
#define LDT (GBM + 4)   // padded leading dim (keeps 16B alignment, breaks bank stride)

template <bool TANH>
__device__ __forceinline__ void gemm_nt_body(const float* __restrict__ A0,
                                             const float* __restrict__ A1, int KA0, int K,
                                             const float* __restrict__ W,
                                             const float* __restrict__ bias,
                                             float* __restrict__ C, int N) {
    __shared__ float As[GBK][LDT];
    __shared__ float Ws[GBK][LDT];
    const int tid = threadIdx.x;
    const int tn = tid & 15;   // col micro-group (consecutive lanes -> consecutive cols)
    const int tm = tid >> 4;   // row micro-group
    const int r0 = blockIdx.y * GBM;
    const int c0 = blockIdx.x * GBN;
    const int lr = tid >> 3;         // 0..31 loader row
    const int lk = (tid & 7) * 4;    // 0..28 loader k (float4)

    float acc[4][4] = {};

    for (int kt = 0; kt < K; kt += GBK) {
#pragma unroll
        for (int rr = 0; rr < GBM; rr += 32) {
            const int r = r0 + lr + rr;
            const int k = kt + lk;
            float4 av;
            if (k < KA0) av = *(const float4*)&A0[r * KA0 + k];
            else         av = *(const float4*)&A1[r * KA0 + (k - KA0)];
            As[lk + 0][lr + rr] = av.x;
            As[lk + 1][lr + rr] = av.y;
            As[lk + 2][lr + rr] = av.z;
            As[lk + 3][lr + rr] = av.w;
            const float4 wv = *(const float4*)&W[(c0 + lr + rr) * K + k];
            Ws[lk + 0][lr + rr] = wv.x;
            Ws[lk + 1][lr + rr] = wv.y;
            Ws[lk + 2][lr + rr] = wv.z;
            Ws[lk + 3][lr + rr] = wv.w;
        }
        __syncthreads();
#pragma unroll
        for (int kk = 0; kk < GBK; ++kk) {
            float a[4], b[4];
            *(float4*)a = *(const float4*)&As[kk][tm * 4];
            *(float4*)b = *(const float4*)&Ws[kk][tn * 4];
#pragma unroll
            for (int i = 0; i < 4; ++i)
#pragma unroll
                for (int j = 0; j < 4; ++j) acc[i][j] += a[i] * b[j];
        }
        __syncthreads();
    }

#pragma unroll
    for (int i = 0; i < 4; ++i) {
        const int r = r0 + tm * 4 + i;
        float o[4];
#pragma unroll
        for (int j = 0; j < 4; ++j) {
            float v = acc[i][j] + bias[c0 + tn * 4 + j];
            o[j] = TANH ? tanh_fast(v) : v;
        }
        *(float4*)&C[r * N + c0 + tn * 4] = *(const float4*)o;
    }
}

__global__ __launch_bounds__(256) void proj_gemm(const float* __restrict__ query,
                                                 const float* __restrict__ memory,
                                                 const float* __restrict__ Wq,
                                                 const float* __restrict__ Wk,
                                                 const float* __restrict__ bq,
                                                 const float* __restrict__ bk,
                                                 float* __restrict__ qbuf,
                                                 float* __restrict__ kbuf) {
    if (blockIdx.z == 0)
        gemm_nt_body<false>(query, nullptr, QS_, QS_, Wq, bq, qbuf, H_);
    else
        gemm_nt_body<false>(memory, nullptr, KS_, KS_, Wk, bk, kbuf, H_);
}

__global__ __launch_bounds__(256) void out_gemm(const float* __restrict__ query,
                                                const float* __restrict__ attns,
                                                const float* __restrict__ Wo,
                                                const float* __restrict__ bo,
                                                float* __restrict__ out) {
    gemm_nt_body<true>(query, attns, QS_, QS_ + KS_, Wo, bo, out, QS_);
}

// ---------------------------------------------------------------------------
// Fused logits + softmax + attns. One block per (b, group of 4 q-rows).
// 256 threads = 4 waves. Wave w handles m = w, w+4, ... For each unmasked m:
// lane holds 8 h-slices of q (x4 rows), k, Wl in registers; wave-reduce.
// Masked m are skipped entirely (their softmax weight is exactly 0).
// ---------------------------------------------------------------------------
__global__ __launch_bounds__(256) void attn_fused(const float* __restrict__ memory,
                                                  const int* __restrict__ maskN,
                                                  const float* __restrict__ qbuf,
                                                  const float* __restrict__ kbuf,
                                                  const float* __restrict__ Wl,
                                                  const float* __restrict__ bl,
                                                  float* __restrict__ wout,
                                                  float* __restrict__ attns) {
    const int b = blockIdx.y;
    const int q0 = blockIdx.x * 4;
    const int tid = threadIdx.x;
    const int wid = tid >> 6;
    const int lane = tid & 63;

    __shared__ float slog[4][M_];
    __shared__ float sw[4][M_];
    __shared__ int s_allmask;

    // per-lane register slices
    float qreg[4][8], wlr[8];
#pragma unroll
    for (int qi = 0; qi < 4; ++qi) {
        const float* qp = &qbuf[((b << 8) + (q0 + qi)) * H_ + lane * 8];
        *(float4*)&qreg[qi][0] = *(const float4*)qp;
        *(float4*)&qreg[qi][4] = *(const float4*)(qp + 4);
    }
    *(float4*)&wlr[0] = *(const float4*)&Wl[lane * 8];
    *(float4*)&wlr[4] = *(const float4*)&Wl[lane * 8 + 4];
    const float bl0 = bl[0];

    // ---- logits ----
    for (int m = wid; m < M_; m += 4) {
        const int msk = maskN[(b << 8) + m];
        float acc[4] = {0.f, 0.f, 0.f, 0.f};
        if (!msk) {
            const float* kp = &kbuf[((b << 8) + m) * H_ + lane * 8];
            float kr[8];
            *(float4*)&kr[0] = *(const float4*)kp;
            *(float4*)&kr[4] = *(const float4*)(kp + 4);
#pragma unroll
            for (int h = 0; h < 8; ++h) {
                const float kv = kr[h], wv = wlr[h];
#pragma unroll
                for (int qi = 0; qi < 4; ++qi)
                    acc[qi] += tanh_fast(qreg[qi][h] + kv) * wv;
            }
        }
#pragma unroll
        for (int qi = 0; qi < 4; ++qi) {
            float v = acc[qi];
#pragma unroll
            for (int off = 32; off; off >>= 1) v += __shfl_xor(v, off, 64);
            acc[qi] = v;
        }
        if (lane == 0) {
#pragma unroll
            for (int qi = 0; qi < 4; ++qi) slog[qi][m] = acc[qi] + bl0;
        }
    }
    __syncthreads();

    // ---- softmax (wave wid owns row q0+wid; lane owns m = 4*lane..4*lane+3) ----
    {
        const int qi = wid;
        float x[4];
        int mk[4];
#pragma unroll
        for (int j = 0; j < 4; ++j) {
            const int m = lane * 4 + j;
            mk[j] = maskN[(b << 8) + m];
            x[j] = mk[j] ? -1e30f : slog[qi][m];
        }
        float mx = fmaxf(fmaxf(x[0], x[1]), fmaxf(x[2], x[3]));
#pragma unroll
        for (int off = 32; off; off >>= 1) mx = fmaxf(mx, __shfl_xor(mx, off, 64));
        float e[4], s = 0.f;
#pragma unroll
        for (int j = 0; j < 4; ++j) {
            e[j] = mk[j] ? 0.f : fast_exp2((x[j] - mx) * 1.4426950408889634f);
            s += e[j];
        }
#pragma unroll
        for (int off = 32; off; off >>= 1) s += __shfl_xor(s, off, 64);
        float w4[4];
        if (s > 0.f) {
            const float inv = 1.0f / s;
#pragma unroll
            for (int j = 0; j < 4; ++j) w4[j] = e[j] * inv;
        } else {
#pragma unroll
            for (int j = 0; j < 4; ++j) w4[j] = 1.0f / (float)M_;
        }
#pragma unroll
        for (int j = 0; j < 4; ++j) sw[qi][lane * 4 + j] = w4[j];
        *(float4*)&wout[((b << 8) + (q0 + qi)) * M_ + lane * 4] = *(const float4*)w4;
        if (tid == 0) s_allmask = (s <= 0.f) ? 1 : 0;
    }
    __syncthreads();

    // ---- attns: attns[q][d] = sum_m w[q][m] * memory[b][m][d] ----
    {
        const int am = s_allmask;
        float a0[4] = {0.f, 0.f, 0.f, 0.f}, a1[4] = {0.f, 0.f, 0.f, 0.f};
        for (int m = 0; m < M_; ++m) {
            if (maskN[(b << 8) + m] && !am) continue;  // weight exactly 0
            const float m0 = memory[((b << 8) + m) * KS_ + tid];
            const float m1 = memory[((b << 8) + m) * KS_ + 256 + tid];
#pragma unroll
            for (int qi = 0; qi < 4; ++qi) {
                const float wv = sw[qi][m];
                a0[qi] += wv * m0;
                a1[qi] += wv * m1;
            }
        }
#pragma unroll
        for (int qi = 0; qi < 4; ++qi) {
            attns[((b << 8) + (q0 + qi)) * KS_ + tid] = a0[qi];
            attns[((b << 8) + (q0 + qi)) * KS_ + 256 + tid] = a1[qi];
        }
    }
}

// ---------------------------------------------------------------------------
extern "C" void kernel_launch(void* const* d_in, const int* in_sizes, int n_in,
                              void* d_out, int out_size, void* d_ws, size_t ws_size,
                              hipStream_t stream) {
    const float* query  = (const float*)d_in[0];
    const float* memory = (const float*)d_in[1];
    const void*  mask   = d_in[2];
    const float* Wk = (const float*)d_in[3];
    const float* bk = (const float*)d_in[4];
    const float* Wq = (const float*)d_in[5];
    const float* bq = (const float*)d_in[6];
    const float* Wl = (const float*)d_in[7];
    const float* bl = (const float*)d_in[8];
    const float* Wo = (const float*)d_in[9];
    const float* bo = (const float*)d_in[10];

    float* out  = (float*)d_out;                 // [4,256,512]
    float* wout = out + B_ * Q_ * QS_;           // [4,256,256]

    float* ws    = (float*)d_ws;
    float* qbuf  = ws;                            // 524288 floats
    float* kbuf  = ws + 524288;                   // 524288 floats
    float* attns = ws + 1048576;                  // 524288 floats
    int*   maskN = (int*)(ws + 1572864);          // 1024 ints

    hipLaunchKernelGGL(mask_norm, dim3(1), dim3(256), 0, stream,
                       (const unsigned char*)mask, maskN, in_sizes[2]);
    hipLaunchKernelGGL(proj_gemm, dim3(H_ / GBN, (B_ * Q_) / GBM, 2), dim3(256), 0, stream,
                       query, memory, Wq, Wk, bq, bk, qbuf, kbuf);
    hipLaunchKernelGGL(attn_fused, dim3(Q_ / 4, B_), dim3(256), 0, stream,
                       memory, maskN, qbuf, kbuf, Wl, bl, wout, attns);
    hipLaunchKernelGGL(out_gemm, dim3(QS_ / GBN, (B_ * Q_) / GBM), dim3(256), 0, stream,
                       query, attns, Wo, bo, out);
}

// Round 3
// 101.015 us; speedup vs baseline: 1.8971x; 1.8971x over previous
//
#include <hip/hip_runtime.h>

// ---------------------------------------------------------------------------
// FNNAttention (Bahdanau additive attention). B=4, Q=256, M=256, QS=KS=H=512.
//   1. mask_norm  : normalize mask (bool-bytes or int32) -> int32 in ws
//   2. proj_mfma  : q = query@Wq^T+bq ; k = memory@Wk^T+bk  (bf16 MFMA, fp32 out)
//   3. attn_fused : compact unmasked-m list; logits; softmax; weights; attns
//   4. out_mfma   : out = tanh([query|attns]@Wo^T + bo)     (bf16 MFMA)
// ---------------------------------------------------------------------------

#define B_   4
#define Q_   256
#define M_   256
#define H_   512
#define QS_  512
#define KS_  512

#define TSC 2.8853900817779268f   // 2*log2(e): tanh(x)=1-2/(exp2(TSC*x)+1)

typedef __attribute__((ext_vector_type(8))) short bf16x8;
typedef __attribute__((ext_vector_type(4))) float f32x4;

__device__ __forceinline__ float fast_exp2(float x) { return __builtin_amdgcn_exp2f(x); }

__device__ __forceinline__ float tanh_fast(float x) {
    float e = fast_exp2(x * TSC);
    return 1.0f - 2.0f * __builtin_amdgcn_rcpf(e + 1.0f);
}

// ---------------------------------------------------------------------------
// Mask normalization (layout-detecting), same as validated round 1.
// ---------------------------------------------------------------------------
__global__ __launch_bounds__(256) void mask_norm(const unsigned char* __restrict__ raw,
                                                 int* __restrict__ out, int n) {
    __shared__ int flags[4];
    const int tid = threadIdx.x;
    int any = 0;
    for (int i = tid; i < n; i += 256)
        if ((i & 3) && raw[i]) any = 1;
    int wany = __any(any);
    if ((tid & 63) == 0) flags[tid >> 6] = wany ? 1 : 0;
    __syncthreads();
    const int isbool = flags[0] | flags[1] | flags[2] | flags[3];
    const int* ri = (const int*)raw;
    for (int i = tid; i < n; i += 256)
        out[i] = isbool ? (int)raw[i] : ri[i];
}

// ---------------------------------------------------------------------------
// bf16 fragment loader: 8 contiguous fp32 -> 8 bf16 (round-to-nearest).
// ---------------------------------------------------------------------------
__device__ __forceinline__ bf16x8 load_cvt_frag(const float* __restrict__ p) {
    const float4 lo = *(const float4*)p;
    const float4 hi = *(const float4*)(p + 4);
    float f[8] = {lo.x, lo.y, lo.z, lo.w, hi.x, hi.y, hi.z, hi.w};
    union { bf16x8 v; unsigned short u[8]; } r;
#pragma unroll
    for (int j = 0; j < 8; ++j) {
        unsigned b = __builtin_bit_cast(unsigned, f[j]);
        r.u[j] = (unsigned short)((b + 0x8000u) >> 16);
    }
    return r.v;
}

// ---------------------------------------------------------------------------
// LDS-free MFMA NT-GEMM. Each wave computes one 16x16 tile of
//   C[r][c] = act( sum_k A(r,k) * W[c][k] + bias[c] )
// with A(r,k) the virtual concat [A0 | A1]. Fragments (16x16x32_bf16):
//   A: lane l -> row = l&15, k = kt + (l>>4)*8 + j    (j=0..7 contiguous)
//   B: lane l -> col = l&15, k = kt + (l>>4)*8 + j
//   D: reg j  -> row = (l>>4)*4 + j, col = l&15        [measured m89]
// Block = 4 waves = 4 consecutive m-tiles. grid.x = N/16, grid.y = M/64.
// ---------------------------------------------------------------------------
template <bool TANH>
__device__ __forceinline__ void mfma_gemm_body(const float* __restrict__ A0,
                                               const float* __restrict__ A1,
                                               int KA0, int K,
                                               const float* __restrict__ W,
                                               const float* __restrict__ bias,
                                               float* __restrict__ C, int N) {
    const int lane = threadIdx.x & 63;
    const int wid  = threadIdx.x >> 6;
    const int mt = blockIdx.y * 4 + wid;
    const int nt = blockIdx.x;
    const int arow = mt * 16 + (lane & 15);
    const int wrow = nt * 16 + (lane & 15);
    const int koff = (lane >> 4) * 8;
    const int KA1 = K - KA0;

    f32x4 acc0 = {0.f, 0.f, 0.f, 0.f};
    f32x4 acc1 = {0.f, 0.f, 0.f, 0.f};
#pragma unroll 4
    for (int kt = 0; kt < K; kt += 64) {
        {
            const int k = kt + koff;
            const float* ap = (k < KA0) ? &A0[arow * KA0 + k] : &A1[arow * KA1 + (k - KA0)];
            bf16x8 a = load_cvt_frag(ap);
            bf16x8 b = load_cvt_frag(&W[wrow * K + k]);
            acc0 = __builtin_amdgcn_mfma_f32_16x16x32_bf16(a, b, acc0, 0, 0, 0);
        }
        {
            const int k = kt + 32 + koff;
            const float* ap = (k < KA0) ? &A0[arow * KA0 + k] : &A1[arow * KA1 + (k - KA0)];
            bf16x8 a = load_cvt_frag(ap);
            bf16x8 b = load_cvt_frag(&W[wrow * K + k]);
            acc1 = __builtin_amdgcn_mfma_f32_16x16x32_bf16(a, b, acc1, 0, 0, 0);
        }
    }
    const int col = nt * 16 + (lane & 15);
    const float bv = bias[col];
    const int r0 = mt * 16 + (lane >> 4) * 4;
#pragma unroll
    for (int j = 0; j < 4; ++j) {
        float v = acc0[j] + acc1[j] + bv;
        if (TANH) v = tanh_fast(v);
        C[(r0 + j) * N + col] = v;
    }
}

__global__ __launch_bounds__(256) void proj_mfma(const float* __restrict__ query,
                                                 const float* __restrict__ memory,
                                                 const float* __restrict__ Wq,
                                                 const float* __restrict__ Wk,
                                                 const float* __restrict__ bq,
                                                 const float* __restrict__ bk,
                                                 float* __restrict__ qbuf,
                                                 float* __restrict__ kbuf) {
    if (blockIdx.z == 0)
        mfma_gemm_body<false>(query, nullptr, QS_, QS_, Wq, bq, qbuf, H_);
    else
        mfma_gemm_body<false>(memory, nullptr, KS_, KS_, Wk, bk, kbuf, H_);
}

__global__ __launch_bounds__(256) void out_mfma(const float* __restrict__ query,
                                                const float* __restrict__ attns,
                                                const float* __restrict__ Wo,
                                                const float* __restrict__ bo,
                                                float* __restrict__ out) {
    mfma_gemm_body<true>(query, attns, QS_, QS_ + KS_, Wo, bo, out, QS_);
}

// ---------------------------------------------------------------------------
// Fused logits + softmax + attns. Block = (b, 4 q-rows), 1024 threads (16
// waves). Phase 0 compacts the unmasked m into s_list (ballot+popc) so waves
// are load-balanced and masked m cost nothing. Phase 1: wave per m; lane
// holds 8 h-slices; logits = sumWL - 2*sum(wl*rcp(exp2(qs+ks)+1)) + bl.
// Phase 2: softmax per q-row (wave per row). Phase 3: attns (512 threads).
// ---------------------------------------------------------------------------
__global__ __launch_bounds__(1024) void attn_fused(const float* __restrict__ memory,
                                                   const int* __restrict__ maskN,
                                                   const float* __restrict__ qbuf,
                                                   const float* __restrict__ kbuf,
                                                   const float* __restrict__ Wl,
                                                   const float* __restrict__ bl,
                                                   float* __restrict__ wout,
                                                   float* __restrict__ attns) {
    const int b = blockIdx.y;
    const int q0 = blockIdx.x * 4;
    const int tid = threadIdx.x;
    const int wid = tid >> 6;
    const int lane = tid & 63;

    __shared__ float slog[4][M_];
    __shared__ float swt[4][M_];
    __shared__ int s_list[M_];
    __shared__ int s_base[4];
    __shared__ int s_cnt;
    __shared__ int s_allmask;

    // ---- phase 0: compact unmasked m list ----
    int msk_ = 1, prefix_ = 0;
    if (tid < 256) {
        msk_ = maskN[(b << 8) + tid];
        unsigned long long vote = __ballot(msk_ == 0);
        prefix_ = __popcll(vote & ((1ull << lane) - 1ull));
        if (lane == 0) s_base[wid] = __popcll(vote);
    }
    __syncthreads();
    if (tid == 0) {
        int s = 0;
#pragma unroll
        for (int i = 0; i < 4; ++i) { int c = s_base[i]; s_base[i] = s; s += c; }
        s_cnt = s;
    }
    __syncthreads();
    if (tid < 256 && !msk_) s_list[s_base[wid] + prefix_] = tid;

    // per-lane register slices (prescaled q)
    float qreg[4][8], wlr[8];
#pragma unroll
    for (int qi = 0; qi < 4; ++qi) {
        const float* qp = &qbuf[((b << 8) + (q0 + qi)) * H_ + lane * 8];
        float4 a = *(const float4*)qp;
        float4 c = *(const float4*)(qp + 4);
        qreg[qi][0] = a.x * TSC; qreg[qi][1] = a.y * TSC;
        qreg[qi][2] = a.z * TSC; qreg[qi][3] = a.w * TSC;
        qreg[qi][4] = c.x * TSC; qreg[qi][5] = c.y * TSC;
        qreg[qi][6] = c.z * TSC; qreg[qi][7] = c.w * TSC;
    }
    *(float4*)&wlr[0] = *(const float4*)&Wl[lane * 8];
    *(float4*)&wlr[4] = *(const float4*)&Wl[lane * 8 + 4];
    const float bl0 = bl[0];

    // sumWL = sum over all 512 h of Wl[h] (same in every wave)
    float sumWL = wlr[0] + wlr[1] + wlr[2] + wlr[3] + wlr[4] + wlr[5] + wlr[6] + wlr[7];
#pragma unroll
    for (int off = 32; off; off >>= 1) sumWL += __shfl_xor(sumWL, off, 64);

    __syncthreads();
    const int cnt = s_cnt;

    // ---- phase 1: logits over compacted list ----
    for (int idx = wid; idx < cnt; idx += 16) {
        const int m = s_list[idx];
        float kr[8];
        const float* kp = &kbuf[((b << 8) + m) * H_ + lane * 8];
        *(float4*)&kr[0] = *(const float4*)kp;
        *(float4*)&kr[4] = *(const float4*)(kp + 4);
        float acc[4] = {0.f, 0.f, 0.f, 0.f};
#pragma unroll
        for (int h = 0; h < 8; ++h) {
            const float ks = kr[h] * TSC;
            const float wv = wlr[h];
#pragma unroll
            for (int qi = 0; qi < 4; ++qi) {
                const float e = fast_exp2(qreg[qi][h] + ks);
                const float r = __builtin_amdgcn_rcpf(e + 1.0f);
                acc[qi] = fmaf(wv, r, acc[qi]);
            }
        }
#pragma unroll
        for (int qi = 0; qi < 4; ++qi) {
            float v = acc[qi];
#pragma unroll
            for (int off = 32; off; off >>= 1) v += __shfl_xor(v, off, 64);
            if (lane == 0) slog[qi][m] = sumWL - 2.0f * v + bl0;
        }
    }
    __syncthreads();

    // ---- phase 2: softmax (wave wid < 4 owns row q0+wid) ----
    if (wid < 4) {
        const int qi = wid;
        float x[4];
        int mk[4];
#pragma unroll
        for (int j = 0; j < 4; ++j) {
            const int m = lane * 4 + j;
            mk[j] = maskN[(b << 8) + m];
            x[j] = mk[j] ? -1e30f : slog[qi][m];
        }
        float mx = fmaxf(fmaxf(x[0], x[1]), fmaxf(x[2], x[3]));
#pragma unroll
        for (int off = 32; off; off >>= 1) mx = fmaxf(mx, __shfl_xor(mx, off, 64));
        float e[4], s = 0.f;
#pragma unroll
        for (int j = 0; j < 4; ++j) {
            e[j] = mk[j] ? 0.f : fast_exp2((x[j] - mx) * 1.4426950408889634f);
            s += e[j];
        }
#pragma unroll
        for (int off = 32; off; off >>= 1) s += __shfl_xor(s, off, 64);
        float w4[4];
        if (s > 0.f) {
            const float inv = 1.0f / s;
#pragma unroll
            for (int j = 0; j < 4; ++j) w4[j] = e[j] * inv;
        } else {
#pragma unroll
            for (int j = 0; j < 4; ++j) w4[j] = 1.0f / (float)M_;
        }
#pragma unroll
        for (int j = 0; j < 4; ++j) swt[qi][lane * 4 + j] = w4[j];
        *(float4*)&wout[((b << 8) + (q0 + qi)) * M_ + lane * 4] = *(const float4*)w4;
        if (tid == 0) s_allmask = (s <= 0.f) ? 1 : 0;
    }
    __syncthreads();

    // ---- phase 3: attns[q][d] = sum_m w[q][m] * memory[b][m][d] ----
    if (tid < KS_) {
        const int am = s_allmask;
        float a[4] = {0.f, 0.f, 0.f, 0.f};
        if (!am) {
            for (int idx = 0; idx < cnt; ++idx) {
                const int m = s_list[idx];
                const float mv = memory[((b << 8) + m) * KS_ + tid];
#pragma unroll
                for (int qi = 0; qi < 4; ++qi) a[qi] = fmaf(swt[qi][m], mv, a[qi]);
            }
        } else {
            for (int m = 0; m < M_; ++m) {
                const float mv = memory[((b << 8) + m) * KS_ + tid];
#pragma unroll
                for (int qi = 0; qi < 4; ++qi) a[qi] = fmaf(swt[qi][m], mv, a[qi]);
            }
        }
#pragma unroll
        for (int qi = 0; qi < 4; ++qi)
            attns[((b << 8) + (q0 + qi)) * KS_ + tid] = a[qi];
    }
}

// ---------------------------------------------------------------------------
extern "C" void kernel_launch(void* const* d_in, const int* in_sizes, int n_in,
                              void* d_out, int out_size, void* d_ws, size_t ws_size,
                              hipStream_t stream) {
    const float* query  = (const float*)d_in[0];
    const float* memory = (const float*)d_in[1];
    const void*  mask   = d_in[2];
    const float* Wk = (const float*)d_in[3];
    const float* bk = (const float*)d_in[4];
    const float* Wq = (const float*)d_in[5];
    const float* bq = (const float*)d_in[6];
    const float* Wl = (const float*)d_in[7];
    const float* bl = (const float*)d_in[8];
    const float* Wo = (const float*)d_in[9];
    const float* bo = (const float*)d_in[10];

    float* out  = (float*)d_out;                 // [4,256,512]
    float* wout = out + B_ * Q_ * QS_;           // [4,256,256]

    float* ws    = (float*)d_ws;
    float* qbuf  = ws;                            // 524288 floats
    float* kbuf  = ws + 524288;                   // 524288 floats
    float* attns = ws + 1048576;                  // 524288 floats
    int*   maskN = (int*)(ws + 1572864);          // 1024 ints

    hipLaunchKernelGGL(mask_norm, dim3(1), dim3(256), 0, stream,
                       (const unsigned char*)mask, maskN, in_sizes[2]);
    hipLaunchKernelGGL(proj_mfma, dim3(H_ / 16, (B_ * Q_) / 64, 2), dim3(256), 0, stream,
                       query, memory, Wq, Wk, bq, bk, qbuf, kbuf);
    hipLaunchKernelGGL(attn_fused, dim3(Q_ / 4, B_), dim3(1024), 0, stream,
                       memory, maskN, qbuf, kbuf, Wl, bl, wout, attns);
    hipLaunchKernelGGL(out_mfma, dim3(QS_ / 16, (B_ * Q_) / 64), dim3(256), 0, stream,
                       query, attns, Wo, bo, out);
}

// Round 4
// 63.718 us; speedup vs baseline: 3.0075x; 1.5853x over previous
//
#include <hip/hip_runtime.h>

// ---------------------------------------------------------------------------
// FNNAttention (Bahdanau additive attention). B=4, Q=256, M=256, QS=KS=H=512.
//   1. prep      : fp32->bf16 copies of query/memory/Wq/Wk/Wo + mask norm
//   2. proj_mfma : Eq=exp2(TSC*(query@Wq^T+bq)), Ek=... (bf16 MFMA, 32x32/wave)
//   3. attn_fused: logits via Eq*Ek (1 trans/elem), softmax, weights, attns(bf16)
//   4. out_mfma  : out = tanh([query|attns]@Wo^T + bo) (pure bf16 MFMA)
// tanh(x) = 1 - 2/(exp2(TSC*x)+1), TSC = 2*log2(e).
// ---------------------------------------------------------------------------

#define B_   4
#define Q_   256
#define M_   256
#define H_   512
#define QS_  512
#define KS_  512

#define TSC 2.8853900817779268f

typedef __attribute__((ext_vector_type(8))) short bf16x8;
typedef __attribute__((ext_vector_type(4))) float f32x4;

__device__ __forceinline__ float fast_exp2(float x) { return __builtin_amdgcn_exp2f(x); }

__device__ __forceinline__ float tanh_fast(float x) {
    float e = fast_exp2(x * TSC);
    return 1.0f - 2.0f * __builtin_amdgcn_rcpf(e + 1.0f);
}

__device__ __forceinline__ unsigned short rne_bf16(float f) {
    unsigned b = __builtin_bit_cast(unsigned, f);
    return (unsigned short)((b + 0x7FFFu + ((b >> 16) & 1u)) >> 16);
}

__device__ __forceinline__ bf16x8 cvt8(const float* __restrict__ p) {
    const float4 lo = *(const float4*)p;
    const float4 hi = *(const float4*)(p + 4);
    float f[8] = {lo.x, lo.y, lo.z, lo.w, hi.x, hi.y, hi.z, hi.w};
    union { bf16x8 v; unsigned short u[8]; } r;
#pragma unroll
    for (int j = 0; j < 8; ++j) r.u[j] = rne_bf16(f[j]);
    return r.v;
}

// ---------------------------------------------------------------------------
// prep: blocks 0..1023 convert 2.1M floats -> bf16 (8 per thread);
// block 1024 normalizes the mask (layout-detecting, validated round 1).
// Segments (units of 8 floats): query 65536 | memory 65536 | Wq 32768 |
// Wk 32768 | Wo 65536  (total 262144 = 1024 blocks * 256 threads).
// ---------------------------------------------------------------------------
__global__ __launch_bounds__(256) void prep(const float* __restrict__ query,
                                            const float* __restrict__ memory,
                                            const float* __restrict__ Wq,
                                            const float* __restrict__ Wk,
                                            const float* __restrict__ Wo,
                                            const unsigned char* __restrict__ mask,
                                            unsigned short* __restrict__ qbf,
                                            unsigned short* __restrict__ mbf,
                                            unsigned short* __restrict__ wqbf,
                                            unsigned short* __restrict__ wkbf,
                                            unsigned short* __restrict__ wobf,
                                            int* __restrict__ maskN, int nmask) {
    if (blockIdx.x == 1024) {
        __shared__ int flags[4];
        const int tid = threadIdx.x;
        int any = 0;
        for (int i = tid; i < nmask; i += 256)
            if ((i & 3) && mask[i]) any = 1;
        int wany = __any(any);
        if ((tid & 63) == 0) flags[tid >> 6] = wany ? 1 : 0;
        __syncthreads();
        const int isbool = flags[0] | flags[1] | flags[2] | flags[3];
        const int* ri = (const int*)mask;
        for (int i = tid; i < nmask; i += 256)
            maskN[i] = isbool ? (int)mask[i] : ri[i];
        return;
    }
    const int u = blockIdx.x * 256 + threadIdx.x;
    const float* src;
    unsigned short* dst;
    int off;
    if (u < 131072) {
        if (u < 65536) { src = query;  dst = qbf; off = u; }
        else           { src = memory; dst = mbf; off = u - 65536; }
    } else if (u < 196608) {
        if (u < 163840) { src = Wq; dst = wqbf; off = u - 131072; }
        else            { src = Wk; dst = wkbf; off = u - 163840; }
    } else { src = Wo; dst = wobf; off = u - 196608; }
    const int i = off * 8;
    *(bf16x8*)&dst[i] = cvt8(&src[i]);
}

// ---------------------------------------------------------------------------
// proj: both projections, 32x32 output per wave, bf16 MFMA 16x16x32.
// Epilogue stores E = exp2(TSC*(acc+bias)) -- q,k are only ever used via E.
// grid = 256 blocks x 4 waves = 1024 wave-tiles (512 per GEMM).
// Fragment map: A/B lane l -> row/col = l&15, k = kt + (l>>4)*8 + j.
// D: reg j -> row (l>>4)*4+j, col l&15  [measured m89].
// ---------------------------------------------------------------------------
__global__ __launch_bounds__(256) void proj_mfma(const unsigned short* __restrict__ qbf,
                                                 const unsigned short* __restrict__ mbf,
                                                 const unsigned short* __restrict__ wqbf,
                                                 const unsigned short* __restrict__ wkbf,
                                                 const float* __restrict__ bq,
                                                 const float* __restrict__ bk,
                                                 float* __restrict__ Eq,
                                                 float* __restrict__ Ek) {
    const int lane = threadIdx.x & 63;
    const int wid  = threadIdx.x >> 6;
    const int gt = blockIdx.x * 4 + wid;   // 0..1023
    const int z  = gt >> 9;
    const int t  = gt & 511;
    const int tm = t >> 4;                 // 0..31
    const int tn = t & 15;                 // 0..15
    const unsigned short* A = z ? mbf : qbf;
    const unsigned short* W = z ? wkbf : wqbf;
    const float* bias = z ? bk : bq;
    float* C = z ? Ek : Eq;

    const int rA = tm * 32 + (lane & 15);
    const int rB = tn * 32 + (lane & 15);
    const int ko = (lane >> 4) * 8;

    f32x4 acc00 = {0,0,0,0}, acc01 = {0,0,0,0}, acc10 = {0,0,0,0}, acc11 = {0,0,0,0};
#pragma unroll
    for (int kt = 0; kt < 512; kt += 32) {
        bf16x8 a0 = *(const bf16x8*)&A[rA * 512 + kt + ko];
        bf16x8 a1 = *(const bf16x8*)&A[(rA + 16) * 512 + kt + ko];
        bf16x8 b0 = *(const bf16x8*)&W[rB * 512 + kt + ko];
        bf16x8 b1 = *(const bf16x8*)&W[(rB + 16) * 512 + kt + ko];
        acc00 = __builtin_amdgcn_mfma_f32_16x16x32_bf16(a0, b0, acc00, 0, 0, 0);
        acc01 = __builtin_amdgcn_mfma_f32_16x16x32_bf16(a0, b1, acc01, 0, 0, 0);
        acc10 = __builtin_amdgcn_mfma_f32_16x16x32_bf16(a1, b0, acc10, 0, 0, 0);
        acc11 = __builtin_amdgcn_mfma_f32_16x16x32_bf16(a1, b1, acc11, 0, 0, 0);
    }
    const int col = tn * 32 + (lane & 15);
    const int r0  = tm * 32 + (lane >> 4) * 4;
    const float bv0 = bias[col], bv1 = bias[col + 16];
#pragma unroll
    for (int j = 0; j < 4; ++j) {
        C[(r0 + j) * 512 + col]           = fast_exp2(TSC * (acc00[j] + bv0));
        C[(r0 + j) * 512 + col + 16]      = fast_exp2(TSC * (acc01[j] + bv1));
        C[(r0 + 16 + j) * 512 + col]      = fast_exp2(TSC * (acc10[j] + bv0));
        C[(r0 + 16 + j) * 512 + col + 16] = fast_exp2(TSC * (acc11[j] + bv1));
    }
}

// ---------------------------------------------------------------------------
// out: out = tanh([query|attns] @ Wo^T + bo), pure bf16 MFMA, 32x32/wave.
// K = 1024 split as two 512 loops (qbf then abf) -- no per-step branch.
// grid = 128 blocks x 4 waves = 512 wave-tiles.
// ---------------------------------------------------------------------------
__global__ __launch_bounds__(256) void out_mfma(const unsigned short* __restrict__ qbf,
                                                const unsigned short* __restrict__ abf,
                                                const unsigned short* __restrict__ wobf,
                                                const float* __restrict__ bo,
                                                float* __restrict__ out) {
    const int lane = threadIdx.x & 63;
    const int wid  = threadIdx.x >> 6;
    const int t  = blockIdx.x * 4 + wid;   // 0..511
    const int tm = t >> 4;                 // 0..31
    const int tn = t & 15;                 // 0..15
    const int rA = tm * 32 + (lane & 15);
    const int rB = tn * 32 + (lane & 15);
    const int ko = (lane >> 4) * 8;

    f32x4 acc00 = {0,0,0,0}, acc01 = {0,0,0,0}, acc10 = {0,0,0,0}, acc11 = {0,0,0,0};
#pragma unroll 8
    for (int kt = 0; kt < 512; kt += 32) {
        bf16x8 a0 = *(const bf16x8*)&qbf[rA * 512 + kt + ko];
        bf16x8 a1 = *(const bf16x8*)&qbf[(rA + 16) * 512 + kt + ko];
        bf16x8 b0 = *(const bf16x8*)&wobf[rB * 1024 + kt + ko];
        bf16x8 b1 = *(const bf16x8*)&wobf[(rB + 16) * 1024 + kt + ko];
        acc00 = __builtin_amdgcn_mfma_f32_16x16x32_bf16(a0, b0, acc00, 0, 0, 0);
        acc01 = __builtin_amdgcn_mfma_f32_16x16x32_bf16(a0, b1, acc01, 0, 0, 0);
        acc10 = __builtin_amdgcn_mfma_f32_16x16x32_bf16(a1, b0, acc10, 0, 0, 0);
        acc11 = __builtin_amdgcn_mfma_f32_16x16x32_bf16(a1, b1, acc11, 0, 0, 0);
    }
#pragma unroll 8
    for (int kt = 0; kt < 512; kt += 32) {
        bf16x8 a0 = *(const bf16x8*)&abf[rA * 512 + kt + ko];
        bf16x8 a1 = *(const bf16x8*)&abf[(rA + 16) * 512 + kt + ko];
        bf16x8 b0 = *(const bf16x8*)&wobf[rB * 1024 + 512 + kt + ko];
        bf16x8 b1 = *(const bf16x8*)&wobf[(rB + 16) * 1024 + 512 + kt + ko];
        acc00 = __builtin_amdgcn_mfma_f32_16x16x32_bf16(a0, b0, acc00, 0, 0, 0);
        acc01 = __builtin_amdgcn_mfma_f32_16x16x32_bf16(a0, b1, acc01, 0, 0, 0);
        acc10 = __builtin_amdgcn_mfma_f32_16x16x32_bf16(a1, b0, acc10, 0, 0, 0);
        acc11 = __builtin_amdgcn_mfma_f32_16x16x32_bf16(a1, b1, acc11, 0, 0, 0);
    }
    const int col = tn * 32 + (lane & 15);
    const int r0  = tm * 32 + (lane >> 4) * 4;
    const float bv0 = bo[col], bv1 = bo[col + 16];
#pragma unroll
    for (int j = 0; j < 4; ++j) {
        out[(r0 + j) * 512 + col]           = tanh_fast(acc00[j] + bv0);
        out[(r0 + j) * 512 + col + 16]      = tanh_fast(acc01[j] + bv1);
        out[(r0 + 16 + j) * 512 + col]      = tanh_fast(acc10[j] + bv0);
        out[(r0 + 16 + j) * 512 + col + 16] = tanh_fast(acc11[j] + bv1);
    }
}

// ---------------------------------------------------------------------------
// Fused logits + softmax + attns. Block = (b, 4 q-rows), 1024 threads.
// Phase 1 uses precomputed Eq,Ek: tanh term = rcp(Eq*Ek + 1) -- 1 trans/elem.
// logits = sumWL - 2*sum(wl*r) + bl.  attns written as bf16.
// ---------------------------------------------------------------------------
__global__ __launch_bounds__(1024) void attn_fused(const float* __restrict__ memory,
                                                   const int* __restrict__ maskN,
                                                   const float* __restrict__ Eq,
                                                   const float* __restrict__ Ek,
                                                   const float* __restrict__ Wl,
                                                   const float* __restrict__ bl,
                                                   float* __restrict__ wout,
                                                   unsigned short* __restrict__ abf) {
    const int b = blockIdx.y;
    const int q0 = blockIdx.x * 4;
    const int tid = threadIdx.x;
    const int wid = tid >> 6;
    const int lane = tid & 63;

    __shared__ float slog[4][M_];
    __shared__ float swt[4][M_];
    __shared__ int s_list[M_];
    __shared__ int s_base[4];
    __shared__ int s_cnt;
    __shared__ int s_allmask;

    // ---- phase 0: compact unmasked m list ----
    int msk_ = 1, prefix_ = 0;
    if (tid < 256) {
        msk_ = maskN[(b << 8) + tid];
        unsigned long long vote = __ballot(msk_ == 0);
        prefix_ = __popcll(vote & ((1ull << lane) - 1ull));
        if (lane == 0) s_base[wid] = __popcll(vote);
    }
    __syncthreads();
    if (tid == 0) {
        int s = 0;
#pragma unroll
        for (int i = 0; i < 4; ++i) { int c = s_base[i]; s_base[i] = s; s += c; }
        s_cnt = s;
    }
    __syncthreads();
    if (tid < 256 && !msk_) s_list[s_base[wid] + prefix_] = tid;

    // per-lane register slices (Eq already exponentiated)
    float qreg[4][8], wlr[8];
#pragma unroll
    for (int qi = 0; qi < 4; ++qi) {
        const float* qp = &Eq[((b << 8) + (q0 + qi)) * H_ + lane * 8];
        *(float4*)&qreg[qi][0] = *(const float4*)qp;
        *(float4*)&qreg[qi][4] = *(const float4*)(qp + 4);
    }
    *(float4*)&wlr[0] = *(const float4*)&Wl[lane * 8];
    *(float4*)&wlr[4] = *(const float4*)&Wl[lane * 8 + 4];
    const float bl0 = bl[0];

    float sumWL = wlr[0] + wlr[1] + wlr[2] + wlr[3] + wlr[4] + wlr[5] + wlr[6] + wlr[7];
#pragma unroll
    for (int off = 32; off; off >>= 1) sumWL += __shfl_xor(sumWL, off, 64);

    __syncthreads();
    const int cnt = s_cnt;

    // ---- phase 1: logits over compacted list (1 rcp per element) ----
    for (int idx = wid; idx < cnt; idx += 16) {
        const int m = s_list[idx];
        float kr[8];
        const float* kp = &Ek[((b << 8) + m) * H_ + lane * 8];
        *(float4*)&kr[0] = *(const float4*)kp;
        *(float4*)&kr[4] = *(const float4*)(kp + 4);
        float acc[4] = {0.f, 0.f, 0.f, 0.f};
#pragma unroll
        for (int h = 0; h < 8; ++h) {
            const float ek = kr[h];
            const float wv = wlr[h];
#pragma unroll
            for (int qi = 0; qi < 4; ++qi) {
                const float e = qreg[qi][h] * ek;
                const float r = __builtin_amdgcn_rcpf(e + 1.0f);
                acc[qi] = fmaf(wv, r, acc[qi]);
            }
        }
#pragma unroll
        for (int qi = 0; qi < 4; ++qi) {
            float v = acc[qi];
#pragma unroll
            for (int off = 32; off; off >>= 1) v += __shfl_xor(v, off, 64);
            if (lane == 0) slog[qi][m] = sumWL - 2.0f * v + bl0;
        }
    }
    __syncthreads();

    // ---- phase 2: softmax (wave wid < 4 owns row q0+wid) ----
    if (wid < 4) {
        const int qi = wid;
        float x[4];
        int mk[4];
#pragma unroll
        for (int j = 0; j < 4; ++j) {
            const int m = lane * 4 + j;
            mk[j] = maskN[(b << 8) + m];
            x[j] = mk[j] ? -1e30f : slog[qi][m];
        }
        float mx = fmaxf(fmaxf(x[0], x[1]), fmaxf(x[2], x[3]));
#pragma unroll
        for (int off = 32; off; off >>= 1) mx = fmaxf(mx, __shfl_xor(mx, off, 64));
        float e[4], s = 0.f;
#pragma unroll
        for (int j = 0; j < 4; ++j) {
            e[j] = mk[j] ? 0.f : fast_exp2((x[j] - mx) * 1.4426950408889634f);
            s += e[j];
        }
#pragma unroll
        for (int off = 32; off; off >>= 1) s += __shfl_xor(s, off, 64);
        float w4[4];
        if (s > 0.f) {
            const float inv = 1.0f / s;
#pragma unroll
            for (int j = 0; j < 4; ++j) w4[j] = e[j] * inv;
        } else {
#pragma unroll
            for (int j = 0; j < 4; ++j) w4[j] = 1.0f / (float)M_;
        }
#pragma unroll
        for (int j = 0; j < 4; ++j) swt[qi][lane * 4 + j] = w4[j];
        *(float4*)&wout[((b << 8) + (q0 + qi)) * M_ + lane * 4] = *(const float4*)w4;
        if (tid == 0) s_allmask = (s <= 0.f) ? 1 : 0;
    }
    __syncthreads();

    // ---- phase 3: attns[q][d] = sum_m w[q][m]*memory[b][m][d], stored bf16 ----
    if (tid < KS_) {
        const int am = s_allmask;
        float a[4] = {0.f, 0.f, 0.f, 0.f};
        if (!am) {
            for (int idx = 0; idx < cnt; ++idx) {
                const int m = s_list[idx];
                const float mv = memory[((b << 8) + m) * KS_ + tid];
#pragma unroll
                for (int qi = 0; qi < 4; ++qi) a[qi] = fmaf(swt[qi][m], mv, a[qi]);
            }
        } else {
            for (int m = 0; m < M_; ++m) {
                const float mv = memory[((b << 8) + m) * KS_ + tid];
#pragma unroll
                for (int qi = 0; qi < 4; ++qi) a[qi] = fmaf(swt[qi][m], mv, a[qi]);
            }
        }
#pragma unroll
        for (int qi = 0; qi < 4; ++qi)
            abf[((b << 8) + (q0 + qi)) * KS_ + tid] = rne_bf16(a[qi]);
    }
}

// ---------------------------------------------------------------------------
extern "C" void kernel_launch(void* const* d_in, const int* in_sizes, int n_in,
                              void* d_out, int out_size, void* d_ws, size_t ws_size,
                              hipStream_t stream) {
    const float* query  = (const float*)d_in[0];
    const float* memory = (const float*)d_in[1];
    const void*  mask   = d_in[2];
    const float* Wk = (const float*)d_in[3];
    const float* bk = (const float*)d_in[4];
    const float* Wq = (const float*)d_in[5];
    const float* bq = (const float*)d_in[6];
    const float* Wl = (const float*)d_in[7];
    const float* bl = (const float*)d_in[8];
    const float* Wo = (const float*)d_in[9];
    const float* bo = (const float*)d_in[10];

    float* out  = (float*)d_out;                 // [4,256,512]
    float* wout = out + B_ * Q_ * QS_;           // [4,256,256]

    float* ws = (float*)d_ws;
    float*          Eq    = ws;                              // 524288 f32
    float*          Ek    = ws + 524288;                     // 524288 f32
    unsigned short* abf   = (unsigned short*)(ws + 1048576); // 524288 bf16
    unsigned short* qbf   = (unsigned short*)(ws + 1310720); // 524288 bf16
    unsigned short* mbf   = (unsigned short*)(ws + 1572864); // 524288 bf16
    unsigned short* wqbf  = (unsigned short*)(ws + 1835008); // 262144 bf16
    unsigned short* wkbf  = (unsigned short*)(ws + 1966080); // 262144 bf16
    unsigned short* wobf  = (unsigned short*)(ws + 2097152); // 524288 bf16
    int*            maskN = (int*)(ws + 2359296);            // 1024 int

    hipLaunchKernelGGL(prep, dim3(1025), dim3(256), 0, stream,
                       query, memory, Wq, Wk, Wo, (const unsigned char*)mask,
                       qbf, mbf, wqbf, wkbf, wobf, maskN, in_sizes[2]);
    hipLaunchKernelGGL(proj_mfma, dim3(256), dim3(256), 0, stream,
                       qbf, mbf, wqbf, wkbf, bq, bk, Eq, Ek);
    hipLaunchKernelGGL(attn_fused, dim3(Q_ / 4, B_), dim3(1024), 0, stream,
                       memory, maskN, Eq, Ek, Wl, bl, wout, abf);
    hipLaunchKernelGGL(out_mfma, dim3(128), dim3(256), 0, stream,
                       qbf, abf, wobf, bo, out);
}